// Round 5
// baseline (773.984 us; speedup 1.0000x reference)
//
#include <hip/hip_runtime.h>
#include <stdint.h>

// R5: packed-bf16 atomics (global_atomic_pk_add_bf16) halve atomic count+bytes;
// agg is bf16 (halves memset + node staging reads); edge gathers use uint4 (16B).

#define N_NODES 100000
#define N_GRAPH 5000
#define N_EDGE  1000000
#define H 128

typedef unsigned short u16;
typedef __attribute__((ext_vector_type(8))) short short8;
typedef __attribute__((ext_vector_type(4))) float floatx4;

__device__ inline float b2f(u16 x) {
    unsigned u = ((unsigned)x) << 16;
    return __uint_as_float(u);
}
__device__ inline u16 f2b(float f) {
    unsigned u = __float_as_uint(f);
    unsigned r = (u + 0x7FFFu + ((u >> 16) & 1u)) >> 16;  // RNE
    return (u16)r;
}
__device__ inline float silu_f(float x) {
    x = fminf(30.f, fmaxf(-30.f, x));
    return x / (1.0f + __expf(-x));
}
__device__ inline float get_bf(const uint4& v, int j) {
    unsigned w = ((const unsigned*)&v)[j >> 1];
    return b2f((u16)(w >> (16 * (j & 1))));
}
__device__ inline void pk_atomic_add_bf16(u16* addr, unsigned packed) {
    asm volatile("global_atomic_pk_add_bf16 %0, %1, off"
                 :: "v"((unsigned long long)(uintptr_t)addr), "v"(packed) : "memory");
}

// ---------------- dtype probe: flag=1 if inputs are bf16, 0 if fp32 ----------------
__global__ void probe_kernel(const unsigned* __restrict__ nf_raw, int* __restrict__ flag) {
    __shared__ int cnt_s;
    if (threadIdx.x == 0) cnt_s = 0;
    __syncthreads();
    unsigned u = nf_raw[threadIdx.x];
    unsigned e2 = (u >> 7) & 0xFF;
    int in_range = (e2 >= 90 && e2 <= 160) ? 1 : 0;
    atomicAdd(&cnt_s, in_range);
    __syncthreads();
    if (threadIdx.x == 0) *flag = (cnt_s >= 128) ? 1 : 0;
}

// ---------------- LayerNorm: h = LN(node_features) * g + b, bf16 out ----------------
__global__ void ln_kernel(const void* __restrict__ nf, const void* __restrict__ g,
                          const void* __restrict__ b, u16* __restrict__ h,
                          const int* __restrict__ flagp) {
    int bf = *flagp;
    int row = blockIdx.x * 4 + (threadIdx.x >> 6);
    int lane = threadIdx.x & 63;
    if (row >= N_NODES) return;
    float x0, x1;
    if (bf) {
        unsigned v = ((const unsigned*)nf)[(size_t)row * 64 + lane];
        x0 = b2f((u16)(v & 0xFFFF));
        x1 = b2f((u16)(v >> 16));
    } else {
        const float* p = (const float*)nf + (size_t)row * H + lane * 2;
        x0 = p[0]; x1 = p[1];
    }
    float s1 = x0 + x1, s2 = x0 * x0 + x1 * x1;
    #pragma unroll
    for (int off = 32; off >= 1; off >>= 1) {
        s1 += __shfl_xor(s1, off, 64);
        s2 += __shfl_xor(s2, off, 64);
    }
    float mu = s1 * (1.0f / H);
    float var = s2 * (1.0f / H) - mu * mu;
    float rs = rsqrtf(var + 1e-5f);
    float g0, g1, bb0, bb1;
    if (bf) {
        unsigned gv = ((const unsigned*)g)[lane];
        unsigned bv = ((const unsigned*)b)[lane];
        g0 = b2f((u16)(gv & 0xFFFF)); g1 = b2f((u16)(gv >> 16));
        bb0 = b2f((u16)(bv & 0xFFFF)); bb1 = b2f((u16)(bv >> 16));
    } else {
        g0 = ((const float*)g)[lane * 2]; g1 = ((const float*)g)[lane * 2 + 1];
        bb0 = ((const float*)b)[lane * 2]; bb1 = ((const float*)b)[lane * 2 + 1];
    }
    float y0 = (x0 - mu) * rs * g0 + bb0;
    float y1 = (x1 - mu) * rs * g1 + bb1;
    unsigned o = (unsigned)f2b(y0) | ((unsigned)f2b(y1) << 16);
    *(unsigned*)(h + (size_t)row * H + lane * 2) = o;
}

// ---------------- LG[g][c] = b1e[c] + sum_ij ltl(g)_ij * W1e[256+ij][c], bf16 out ----------------
__global__ void lg_kernel(const void* __restrict__ lat, const void* __restrict__ W1e,
                          const void* __restrict__ b1e, u16* __restrict__ LGb,
                          const int* __restrict__ flagp) {
    int bf = *flagp;
    int t = blockIdx.x * 256 + threadIdx.x;
    if (t >= N_GRAPH * 64) return;
    int g = t >> 6, cp = (t & 63) * 2;
    float L[9];
    #pragma unroll
    for (int k = 0; k < 9; k++)
        L[k] = bf ? b2f(((const u16*)lat)[g * 9 + k]) : ((const float*)lat)[g * 9 + k];
    float a0 = bf ? b2f(((const u16*)b1e)[cp])     : ((const float*)b1e)[cp];
    float a1 = bf ? b2f(((const u16*)b1e)[cp + 1]) : ((const float*)b1e)[cp + 1];
    #pragma unroll
    for (int i = 0; i < 3; i++) {
        #pragma unroll
        for (int j = 0; j < 3; j++) {
            float lt = L[i*3] * L[j*3] + L[i*3+1] * L[j*3+1] + L[i*3+2] * L[j*3+2];
            int r = 256 + i * 3 + j;
            float w0 = bf ? b2f(((const u16*)W1e)[(size_t)r * H + cp])     : ((const float*)W1e)[(size_t)r * H + cp];
            float w1 = bf ? b2f(((const u16*)W1e)[(size_t)r * H + cp + 1]) : ((const float*)W1e)[(size_t)r * H + cp + 1];
            a0 += lt * w0;
            a1 += lt * w1;
        }
    }
    LGb[(size_t)g * H + cp] = f2b(a0);
    LGb[(size_t)g * H + cp + 1] = f2b(a1);
}

// ---------------- pack W rows [k0, k0+KT*32) of [Ktot,128] -> MFMA B-fragment layout ----------------
__global__ void pack_kernel(const void* __restrict__ W, u16* __restrict__ out, int k0, int Ktot, int KT,
                            const int* __restrict__ flagp) {
    int bf = *flagp;
    int t = blockIdx.x * 256 + threadIdx.x;
    if (t >= KT * 8 * 64) return;
    int lane = t & 63, nt = (t >> 6) & 7, kt = t >> 9;
    int n = nt * 16 + (lane & 15);
    int kbase = k0 + kt * 32 + ((lane >> 4) << 3);
    u16 vals[8];
    #pragma unroll
    for (int j = 0; j < 8; j++) {
        int k = kbase + j;
        if (k >= Ktot) vals[j] = 0;
        else if (bf) vals[j] = ((const u16*)W)[(size_t)k * H + n];
        else vals[j] = f2b(((const float*)W)[(size_t)k * H + n]);
    }
    uint4 tmp;
    __builtin_memcpy(&tmp, vals, 16);
    *(uint4*)(out + (size_t)t * 8) = tmp;
}

// ---------------- in-degree counts over edge_index[0] ----------------
__global__ void cnt_kernel(const int* __restrict__ ei, int* __restrict__ cnt) {
    int e = blockIdx.x * 256 + threadIdx.x;
    if (e < N_EDGE) atomicAdd(&cnt[ei[e]], 1);
}

// ---------------- uv: U = h @ W1e[0:128], V = h @ W1e[128:256], bf16, no bias/act ----------------
#define UVP 136
__global__ __launch_bounds__(256, 4) void uv_kernel(
    const u16* __restrict__ h, const u16* __restrict__ Wtp, const u16* __restrict__ Wmp,
    u16* __restrict__ U, u16* __restrict__ V) {
    __shared__ u16 sA[64 * UVP];
    int tid = threadIdx.x;
    int lane = tid & 63, w = tid >> 6;
    int r0 = blockIdx.x * 64;

    for (int i = tid; i < 1024; i += 256) {
        int row = i >> 4, c = i & 15;
        int gr = r0 + row; if (gr >= N_NODES) gr = N_NODES - 1;
        uint4 v = *(const uint4*)(h + (size_t)gr * H + c * 8);
        *(uint4*)(&sA[row * UVP + c * 8]) = v;
    }
    __syncthreads();

    const short8* Wt = (const short8*)Wtp;
    const short8* Wm = (const short8*)Wmp;
    int q8 = (lane >> 4) * 8;
    int mrow = lane & 15;
    int q = lane >> 4;

    floatx4 aU[4][2], aV[4][2];
    #pragma unroll
    for (int mt = 0; mt < 4; mt++) {
        aU[mt][0] = (floatx4){0,0,0,0}; aU[mt][1] = (floatx4){0,0,0,0};
        aV[mt][0] = (floatx4){0,0,0,0}; aV[mt][1] = (floatx4){0,0,0,0};
    }
    #pragma unroll
    for (int kt = 0; kt < 4; kt++) {
        short8 bu0 = Wt[(kt * 8 + 2 * w) * 64 + lane];
        short8 bu1 = Wt[(kt * 8 + 2 * w + 1) * 64 + lane];
        short8 bv0 = Wm[(kt * 8 + 2 * w) * 64 + lane];
        short8 bv1 = Wm[(kt * 8 + 2 * w + 1) * 64 + lane];
        #pragma unroll
        for (int mt = 0; mt < 4; mt++) {
            short8 a = *(const short8*)(&sA[(mt * 16 + mrow) * UVP + kt * 32 + q8]);
            aU[mt][0] = __builtin_amdgcn_mfma_f32_16x16x32_bf16(a, bu0, aU[mt][0], 0, 0, 0);
            aU[mt][1] = __builtin_amdgcn_mfma_f32_16x16x32_bf16(a, bu1, aU[mt][1], 0, 0, 0);
            aV[mt][0] = __builtin_amdgcn_mfma_f32_16x16x32_bf16(a, bv0, aV[mt][0], 0, 0, 0);
            aV[mt][1] = __builtin_amdgcn_mfma_f32_16x16x32_bf16(a, bv1, aV[mt][1], 0, 0, 0);
        }
    }
    #pragma unroll
    for (int mt = 0; mt < 4; mt++) {
        #pragma unroll
        for (int nt = 0; nt < 2; nt++) {
            int n = w * 32 + nt * 16 + mrow;
            #pragma unroll
            for (int r = 0; r < 4; r++) {
                int gr = r0 + mt * 16 + q * 4 + r;
                if (gr < N_NODES) {
                    U[(size_t)gr * H + n] = f2b(aU[mt][nt][r]);
                    V[(size_t)gr * H + n] = f2b(aV[mt][nt][r]);
                }
            }
        }
    }
}

// ---------------- fused edge: gather U/V/LG + fd-term + silu -> layer2 GEMM -> pk-bf16 atomic scatter ----------------
#define PP 136

__global__ __launch_bounds__(256, 6) void edge_kernel(
    const u16* __restrict__ U, const u16* __restrict__ V, const u16* __restrict__ LGb,
    const int* __restrict__ ei, const int* __restrict__ e2g,
    const void* __restrict__ fd, const void* __restrict__ W1e,
    const u16* __restrict__ W2p, const void* __restrict__ bias2,
    u16* __restrict__ agg, const int* __restrict__ flagp) {
    __shared__ __align__(16) u16 sP[64 * PP];
    __shared__ int sSrc[64], sDst[64], sG[64];
    __shared__ float sFd[192];
    __shared__ float sB2[128];

    int bf = *flagp;
    int tid = threadIdx.x;
    int lane = tid & 63, w = tid >> 6;
    int e0 = blockIdx.x * 64;

    if (tid < 64) {
        sSrc[tid] = ei[e0 + tid];
        sDst[tid] = ei[N_EDGE + e0 + tid];
        sG[tid] = e2g[e0 + tid];
    }
    if (tid < 128) sB2[tid] = bf ? b2f(((const u16*)bias2)[tid]) : ((const float*)bias2)[tid];
    if (tid < 192) sFd[tid] = bf ? b2f(((const u16*)fd)[(size_t)e0 * 3 + tid])
                                 : ((const float*)fd)[(size_t)e0 * 3 + tid];

    // Wfd = W1e rows 265..267, cols c8..c8+7 (fixed per thread)
    int c8 = (tid & 15) * 8;
    float wf[3][8];
    #pragma unroll
    for (int k = 0; k < 3; k++)
        #pragma unroll
        for (int j = 0; j < 8; j++)
            wf[k][j] = bf ? b2f(((const u16*)W1e)[(size_t)(265 + k) * H + c8 + j])
                          : ((const float*)W1e)[(size_t)(265 + k) * H + c8 + j];
    __syncthreads();

    // gather (uint4) + fd-term + silu -> sP
    for (int i = tid; i < 1024; i += 256) {
        int row = i >> 4;
        int s = sSrc[row], d = sDst[row], g = sG[row];
        uint4 uu = *(const uint4*)(U + (size_t)s * H + c8);
        uint4 vv = *(const uint4*)(V + (size_t)d * H + c8);
        uint4 gg = *(const uint4*)(LGb + (size_t)g * H + c8);
        float f0 = sFd[row * 3], f1 = sFd[row * 3 + 1], f2v = sFd[row * 3 + 2];
        u16 o[8];
        #pragma unroll
        for (int j = 0; j < 8; j++) {
            float val = get_bf(uu, j) + get_bf(vv, j) + get_bf(gg, j)
                      + f0 * wf[0][j] + f1 * wf[1][j] + f2v * wf[2][j];
            o[j] = f2b(silu_f(val));
        }
        uint4 packed;
        __builtin_memcpy(&packed, o, 16);
        *(uint4*)(&sP[row * PP + c8]) = packed;
    }
    __syncthreads();

    const short8* W2v = (const short8*)W2p;
    int q8 = (lane >> 4) * 8;
    int mrow = lane & 15;
    int q = lane >> 4;

    // layer 2: [64,128] @ [128,128]
    floatx4 acc2[4][2];
    #pragma unroll
    for (int mt = 0; mt < 4; mt++) {
        acc2[mt][0] = (floatx4){0,0,0,0};
        acc2[mt][1] = (floatx4){0,0,0,0};
    }
    #pragma unroll
    for (int kt = 0; kt < 4; kt++) {
        short8 bf0 = W2v[(kt * 8 + 2 * w) * 64 + lane];
        short8 bf1 = W2v[(kt * 8 + 2 * w + 1) * 64 + lane];
        #pragma unroll
        for (int mt = 0; mt < 4; mt++) {
            short8 a = *(const short8*)(&sP[(mt * 16 + mrow) * PP + kt * 32 + q8]);
            acc2[mt][0] = __builtin_amdgcn_mfma_f32_16x16x32_bf16(a, bf0, acc2[mt][0], 0, 0, 0);
            acc2[mt][1] = __builtin_amdgcn_mfma_f32_16x16x32_bf16(a, bf1, acc2[mt][1], 0, 0, 0);
        }
    }
    // bias + silu -> packed bf16 atomic scatter into agg[src]
    // lane pair (2k,2k+1) covers column pair (n,n+1); even lane handles rows r=0,1, odd r=2,3.
    int odd = lane & 1;
    int n0 = (w * 32 + mrow) & ~1;   // nt added below
    #pragma unroll
    for (int mt = 0; mt < 4; mt++) {
        #pragma unroll
        for (int nt = 0; nt < 2; nt++) {
            int n = w * 32 + nt * 16 + mrow;
            float bias = sB2[n];
            float sv[4], ov[4];
            #pragma unroll
            for (int r = 0; r < 4; r++) sv[r] = silu_f(acc2[mt][nt][r] + bias);
            #pragma unroll
            for (int r = 0; r < 4; r++) ov[r] = __shfl_xor(sv[r], 1, 64);
            int ncol = (n0 + nt * 16);
            #pragma unroll
            for (int rr = 0; rr < 2; rr++) {
                int r = odd * 2 + rr;
                float lo = odd ? ov[r] : sv[r];
                float hi = odd ? sv[r] : ov[r];
                unsigned packed = (unsigned)f2b(lo) | ((unsigned)f2b(hi) << 16);
                int row = mt * 16 + q * 4 + r;
                pk_atomic_add_bf16(agg + (size_t)sSrc[row] * H + ncol, packed);
            }
        }
    }
}

// ---------------- node MLP + residual ----------------
#define NKP 264

__global__ __launch_bounds__(256, 4) void node_kernel(
    const u16* __restrict__ h, const u16* __restrict__ agg, const int* __restrict__ cnt,
    const void* __restrict__ nf,
    const u16* __restrict__ W1p, const u16* __restrict__ W2p,
    const void* __restrict__ bias1, const void* __restrict__ bias2,
    void* __restrict__ out, const int* __restrict__ flagp) {
    __shared__ __align__(16) u16 sU[64 * NKP];
    __shared__ float sB1[128], sB2[128];
    u16* sA = sU;
    u16* sP = sU;

    int bf = *flagp;
    int tid = threadIdx.x;
    int lane = tid & 63, w = tid >> 6;
    int r0 = blockIdx.x * 64;

    if (tid < 128) sB1[tid] = bf ? b2f(((const u16*)bias1)[tid]) : ((const float*)bias1)[tid];
    else sB2[tid - 128] = bf ? b2f(((const u16*)bias2)[tid - 128]) : ((const float*)bias2)[tid - 128];

    // stage h rows (cols 0..127)
    for (int i = tid; i < 1024; i += 256) {
        int row = i >> 4, c = i & 15;
        int gr = r0 + row; if (gr >= N_NODES) gr = N_NODES - 1;
        uint4 v = *(const uint4*)(h + (size_t)gr * H + c * 8);
        *(uint4*)(&sA[row * NKP + c * 8]) = v;
    }
    // stage agg rows (cols 128..255), bf16 scaled by 1/cnt
    for (int i = tid; i < 1024; i += 256) {
        int row = i >> 4, c = i & 15;
        int gr = r0 + row; if (gr >= N_NODES) gr = N_NODES - 1;
        int cn = cnt[gr];
        float sc = 1.0f / (float)(cn > 0 ? cn : 1);
        uint4 av = *(const uint4*)(agg + (size_t)gr * H + c * 8);
        u16 vv[8];
        #pragma unroll
        for (int j = 0; j < 8; j++) vv[j] = f2b(get_bf(av, j) * sc);
        uint4 tmp;
        __builtin_memcpy(&tmp, vv, 16);
        *(uint4*)(&sA[row * NKP + 128 + c * 8]) = tmp;
    }
    __syncthreads();

    const short8* W1v = (const short8*)W1p;
    const short8* W2v = (const short8*)W2p;
    int q8 = (lane >> 4) * 8;
    int mrow = lane & 15;
    int q = lane >> 4;

    floatx4 acc[4][2];
    #pragma unroll
    for (int mt = 0; mt < 4; mt++) {
        acc[mt][0] = (floatx4){0,0,0,0};
        acc[mt][1] = (floatx4){0,0,0,0};
    }
    #pragma unroll
    for (int kt = 0; kt < 8; kt++) {
        short8 bf0 = W1v[(kt * 8 + 2 * w) * 64 + lane];
        short8 bf1 = W1v[(kt * 8 + 2 * w + 1) * 64 + lane];
        #pragma unroll
        for (int mt = 0; mt < 4; mt++) {
            short8 a = *(const short8*)(&sA[(mt * 16 + mrow) * NKP + kt * 32 + q8]);
            acc[mt][0] = __builtin_amdgcn_mfma_f32_16x16x32_bf16(a, bf0, acc[mt][0], 0, 0, 0);
            acc[mt][1] = __builtin_amdgcn_mfma_f32_16x16x32_bf16(a, bf1, acc[mt][1], 0, 0, 0);
        }
    }
    __syncthreads();

    #pragma unroll
    for (int mt = 0; mt < 4; mt++) {
        #pragma unroll
        for (int nt = 0; nt < 2; nt++) {
            int n = w * 32 + nt * 16 + mrow;
            float bias = sB1[n];
            #pragma unroll
            for (int r = 0; r < 4; r++) {
                int row = mt * 16 + q * 4 + r;
                sP[row * PP + n] = f2b(silu_f(acc[mt][nt][r] + bias));
            }
        }
    }
    __syncthreads();

    floatx4 acc2[4][2];
    #pragma unroll
    for (int mt = 0; mt < 4; mt++) {
        acc2[mt][0] = (floatx4){0,0,0,0};
        acc2[mt][1] = (floatx4){0,0,0,0};
    }
    #pragma unroll
    for (int kt = 0; kt < 4; kt++) {
        short8 bf0 = W2v[(kt * 8 + 2 * w) * 64 + lane];
        short8 bf1 = W2v[(kt * 8 + 2 * w + 1) * 64 + lane];
        #pragma unroll
        for (int mt = 0; mt < 4; mt++) {
            short8 a = *(const short8*)(&sP[(mt * 16 + mrow) * PP + kt * 32 + q8]);
            acc2[mt][0] = __builtin_amdgcn_mfma_f32_16x16x32_bf16(a, bf0, acc2[mt][0], 0, 0, 0);
            acc2[mt][1] = __builtin_amdgcn_mfma_f32_16x16x32_bf16(a, bf1, acc2[mt][1], 0, 0, 0);
        }
    }
    #pragma unroll
    for (int mt = 0; mt < 4; mt++) {
        #pragma unroll
        for (int nt = 0; nt < 2; nt++) {
            int n = w * 32 + nt * 16 + mrow;
            float bias = sB2[n];
            #pragma unroll
            for (int r = 0; r < 4; r++) {
                int row = mt * 16 + q * 4 + r;
                int gr = r0 + row;
                if (gr < N_NODES) {
                    float s = silu_f(acc2[mt][nt][r] + bias);
                    size_t idx = (size_t)gr * H + n;
                    float nv = bf ? b2f(((const u16*)nf)[idx]) : ((const float*)nf)[idx];
                    float o = nv + s;
                    if (bf) ((u16*)out)[idx] = f2b(o);
                    else ((float*)out)[idx] = o;
                }
            }
        }
    }
}

extern "C" void kernel_launch(void* const* d_in, const int* in_sizes, int n_in,
                              void* d_out, int out_size, void* d_ws, size_t ws_size,
                              hipStream_t stream) {
    const void* node_features = d_in[0];
    const void* lattices      = d_in[1];
    const int* edge_index     = (const int*)d_in[2];
    const int* edge2graph     = (const int*)d_in[3];
    const void* frac_diff     = d_in[4];
    const void* W1e = d_in[5];  const void* b1e = d_in[6];
    const void* W2e = d_in[7];  const void* b2e = d_in[8];
    const void* W1n = d_in[9];  const void* b1n = d_in[10];
    const void* W2n = d_in[11]; const void* b2n = d_in[12];
    const void* ln_g = d_in[13];
    const void* ln_b = d_in[14];

    char* ws = (char*)d_ws;
    size_t off = 0;
    u16*   agg = (u16*)(ws + off);              off += (size_t)N_NODES * H * 2;   // 25.6 MB bf16
    int*   cnt = (int*)(ws + off);              off += (size_t)N_NODES * 4;
    size_t zero_bytes = off;
    int*   flag = (int*)(ws + off);             off += 16;
    u16*   h    = (u16*)(ws + off);             off += (size_t)N_NODES * H * 2;   // 25.6 MB
    u16*   LGb  = (u16*)(ws + off);             off += (size_t)N_GRAPH * H * 2;   // 1.28 MB
    u16*   W1tp = (u16*)(ws + off);             off += (size_t)128 * 128 * 2;
    u16*   W1mp = (u16*)(ws + off);             off += (size_t)128 * 128 * 2;
    u16*   W2p  = (u16*)(ws + off);             off += (size_t)128 * 128 * 2;
    u16*   W1np = (u16*)(ws + off);             off += (size_t)256 * 128 * 2;
    u16*   W2np = (u16*)(ws + off);             off += (size_t)128 * 128 * 2;

    // U, V live in d_out (dead until node_kernel writes it).
    u16* U = (u16*)d_out;
    u16* V = (u16*)d_out + (size_t)N_NODES * H;

    hipMemsetAsync(agg, 0, zero_bytes, stream);

    probe_kernel<<<1, 256, 0, stream>>>((const unsigned*)node_features, flag);
    ln_kernel<<<(N_NODES + 3) / 4, 256, 0, stream>>>(node_features, ln_g, ln_b, h, flag);
    lg_kernel<<<(N_GRAPH * 64 + 255) / 256, 256, 0, stream>>>(lattices, W1e, b1e, LGb, flag);
    pack_kernel<<<(4 * 8 * 64 + 255) / 256, 256, 0, stream>>>(W1e, W1tp, 0, 268, 4, flag);
    pack_kernel<<<(4 * 8 * 64 + 255) / 256, 256, 0, stream>>>(W1e, W1mp, 128, 268, 4, flag);
    pack_kernel<<<(4 * 8 * 64 + 255) / 256, 256, 0, stream>>>(W2e, W2p, 0, 128, 4, flag);
    pack_kernel<<<(8 * 8 * 64 + 255) / 256, 256, 0, stream>>>(W1n, W1np, 0, 256, 8, flag);
    pack_kernel<<<(4 * 8 * 64 + 255) / 256, 256, 0, stream>>>(W2n, W2np, 0, 128, 4, flag);
    cnt_kernel<<<(N_EDGE + 255) / 256, 256, 0, stream>>>(edge_index, cnt);

    uv_kernel<<<(N_NODES + 63) / 64, 256, 0, stream>>>(h, W1tp, W1mp, U, V);
    edge_kernel<<<N_EDGE / 64, 256, 0, stream>>>(U, V, LGb, edge_index, edge2graph,
                                                 frac_diff, W1e, W2p, b2e, agg, flag);
    node_kernel<<<(N_NODES + 63) / 64, 256, 0, stream>>>(h, agg, cnt, node_features,
                                                         W1np, W2np, b1n, b2n, d_out, flag);
}

// Round 6
// 614.910 us; speedup vs baseline: 1.2587x; 1.2587x over previous
//
#include <hip/hip_runtime.h>
#include <stdint.h>

// R6: revert pk-bf16 atomics (R5 regression). Counting-sort edges by src
// (cnt -> 3-kernel prefix scan -> 16B-record scatter); edge kernel processes
// src-sorted tiles and does a wave-uniform LDS segmented reduction ->
// ~6x fewer fp32 atomics (L2 atomic throughput was the R4 wall at 308 G/s).

#define N_NODES 100000
#define N_GRAPH 5000
#define N_EDGE  1000000
#define H 128
#define NBLK 391   // ceil(N_NODES/256)

typedef unsigned short u16;
typedef __attribute__((ext_vector_type(8))) short short8;
typedef __attribute__((ext_vector_type(4))) float floatx4;

__device__ inline float b2f(u16 x) {
    unsigned u = ((unsigned)x) << 16;
    return __uint_as_float(u);
}
__device__ inline u16 f2b(float f) {
    unsigned u = __float_as_uint(f);
    unsigned r = (u + 0x7FFFu + ((u >> 16) & 1u)) >> 16;  // RNE
    return (u16)r;
}
__device__ inline float silu_f(float x) {
    x = fminf(30.f, fmaxf(-30.f, x));
    return x / (1.0f + __expf(-x));
}
__device__ inline float get_bf(const uint4& v, int j) {
    unsigned w = ((const unsigned*)&v)[j >> 1];
    return b2f((u16)(w >> (16 * (j & 1))));
}

// ---------------- dtype probe: flag=1 if inputs are bf16, 0 if fp32 ----------------
__global__ void probe_kernel(const unsigned* __restrict__ nf_raw, int* __restrict__ flag) {
    __shared__ int cnt_s;
    if (threadIdx.x == 0) cnt_s = 0;
    __syncthreads();
    unsigned u = nf_raw[threadIdx.x];
    unsigned e2 = (u >> 7) & 0xFF;
    int in_range = (e2 >= 90 && e2 <= 160) ? 1 : 0;
    atomicAdd(&cnt_s, in_range);
    __syncthreads();
    if (threadIdx.x == 0) *flag = (cnt_s >= 128) ? 1 : 0;
}

// ---------------- LayerNorm ----------------
__global__ void ln_kernel(const void* __restrict__ nf, const void* __restrict__ g,
                          const void* __restrict__ b, u16* __restrict__ h,
                          const int* __restrict__ flagp) {
    int bf = *flagp;
    int row = blockIdx.x * 4 + (threadIdx.x >> 6);
    int lane = threadIdx.x & 63;
    if (row >= N_NODES) return;
    float x0, x1;
    if (bf) {
        unsigned v = ((const unsigned*)nf)[(size_t)row * 64 + lane];
        x0 = b2f((u16)(v & 0xFFFF));
        x1 = b2f((u16)(v >> 16));
    } else {
        const float* p = (const float*)nf + (size_t)row * H + lane * 2;
        x0 = p[0]; x1 = p[1];
    }
    float s1 = x0 + x1, s2 = x0 * x0 + x1 * x1;
    #pragma unroll
    for (int off = 32; off >= 1; off >>= 1) {
        s1 += __shfl_xor(s1, off, 64);
        s2 += __shfl_xor(s2, off, 64);
    }
    float mu = s1 * (1.0f / H);
    float var = s2 * (1.0f / H) - mu * mu;
    float rs = rsqrtf(var + 1e-5f);
    float g0, g1, bb0, bb1;
    if (bf) {
        unsigned gv = ((const unsigned*)g)[lane];
        unsigned bv = ((const unsigned*)b)[lane];
        g0 = b2f((u16)(gv & 0xFFFF)); g1 = b2f((u16)(gv >> 16));
        bb0 = b2f((u16)(bv & 0xFFFF)); bb1 = b2f((u16)(bv >> 16));
    } else {
        g0 = ((const float*)g)[lane * 2]; g1 = ((const float*)g)[lane * 2 + 1];
        bb0 = ((const float*)b)[lane * 2]; bb1 = ((const float*)b)[lane * 2 + 1];
    }
    float y0 = (x0 - mu) * rs * g0 + bb0;
    float y1 = (x1 - mu) * rs * g1 + bb1;
    unsigned o = (unsigned)f2b(y0) | ((unsigned)f2b(y1) << 16);
    *(unsigned*)(h + (size_t)row * H + lane * 2) = o;
}

// ---------------- LG[g][c] = b1e[c] + sum_ij ltl(g)_ij * W1e[256+ij][c] ----------------
__global__ void lg_kernel(const void* __restrict__ lat, const void* __restrict__ W1e,
                          const void* __restrict__ b1e, u16* __restrict__ LGb,
                          const int* __restrict__ flagp) {
    int bf = *flagp;
    int t = blockIdx.x * 256 + threadIdx.x;
    if (t >= N_GRAPH * 64) return;
    int g = t >> 6, cp = (t & 63) * 2;
    float L[9];
    #pragma unroll
    for (int k = 0; k < 9; k++)
        L[k] = bf ? b2f(((const u16*)lat)[g * 9 + k]) : ((const float*)lat)[g * 9 + k];
    float a0 = bf ? b2f(((const u16*)b1e)[cp])     : ((const float*)b1e)[cp];
    float a1 = bf ? b2f(((const u16*)b1e)[cp + 1]) : ((const float*)b1e)[cp + 1];
    #pragma unroll
    for (int i = 0; i < 3; i++) {
        #pragma unroll
        for (int j = 0; j < 3; j++) {
            float lt = L[i*3] * L[j*3] + L[i*3+1] * L[j*3+1] + L[i*3+2] * L[j*3+2];
            int r = 256 + i * 3 + j;
            float w0 = bf ? b2f(((const u16*)W1e)[(size_t)r * H + cp])     : ((const float*)W1e)[(size_t)r * H + cp];
            float w1 = bf ? b2f(((const u16*)W1e)[(size_t)r * H + cp + 1]) : ((const float*)W1e)[(size_t)r * H + cp + 1];
            a0 += lt * w0;
            a1 += lt * w1;
        }
    }
    LGb[(size_t)g * H + cp] = f2b(a0);
    LGb[(size_t)g * H + cp + 1] = f2b(a1);
}

// ---------------- pack W rows [k0, k0+KT*32) -> MFMA B-fragment layout ----------------
__global__ void pack_kernel(const void* __restrict__ W, u16* __restrict__ out, int k0, int Ktot, int KT,
                            const int* __restrict__ flagp) {
    int bf = *flagp;
    int t = blockIdx.x * 256 + threadIdx.x;
    if (t >= KT * 8 * 64) return;
    int lane = t & 63, nt = (t >> 6) & 7, kt = t >> 9;
    int n = nt * 16 + (lane & 15);
    int kbase = k0 + kt * 32 + ((lane >> 4) << 3);
    u16 vals[8];
    #pragma unroll
    for (int j = 0; j < 8; j++) {
        int k = kbase + j;
        if (k >= Ktot) vals[j] = 0;
        else if (bf) vals[j] = ((const u16*)W)[(size_t)k * H + n];
        else vals[j] = f2b(((const float*)W)[(size_t)k * H + n]);
    }
    uint4 tmp;
    __builtin_memcpy(&tmp, vals, 16);
    *(uint4*)(out + (size_t)t * 8) = tmp;
}

// ---------------- degree counts over edge_index[0] ----------------
__global__ void cnt_kernel(const int* __restrict__ ei, int* __restrict__ cnt) {
    int e = blockIdx.x * 256 + threadIdx.x;
    if (e < N_EDGE) atomicAdd(&cnt[ei[e]], 1);
}

// ---------------- prefix-scan of degrees -> starts ----------------
__global__ void ps1_kernel(const int* __restrict__ cnt, int* __restrict__ bsum) {
    __shared__ int s[256];
    int i = blockIdx.x * 256 + threadIdx.x;
    s[threadIdx.x] = (i < N_NODES) ? cnt[i] : 0;
    __syncthreads();
    for (int off = 128; off >= 1; off >>= 1) {
        if (threadIdx.x < off) s[threadIdx.x] += s[threadIdx.x + off];
        __syncthreads();
    }
    if (threadIdx.x == 0) bsum[blockIdx.x] = s[0];
}

__global__ void ps2_kernel(const int* __restrict__ bsum, int* __restrict__ boff) {
    __shared__ int s[512];
    int t = threadIdx.x;
    int v = (t < NBLK) ? bsum[t] : 0;
    s[t] = v;
    __syncthreads();
    for (int off = 1; off < 512; off <<= 1) {
        int add = (t >= off) ? s[t - off] : 0;
        __syncthreads();
        s[t] += add;
        __syncthreads();
    }
    if (t < NBLK) boff[t] = s[t] - v;   // exclusive
}

__global__ void ps3_kernel(const int* __restrict__ cnt, const int* __restrict__ boff,
                           int* __restrict__ starts) {
    __shared__ int s[256];
    int b = blockIdx.x;
    int i = b * 256 + threadIdx.x;
    int v = (i < N_NODES) ? cnt[i] : 0;
    s[threadIdx.x] = v;
    __syncthreads();
    for (int off = 1; off < 256; off <<= 1) {
        int add = (threadIdx.x >= off) ? s[threadIdx.x - off] : 0;
        __syncthreads();
        s[threadIdx.x] += add;
        __syncthreads();
    }
    if (i < N_NODES) starts[i] = boff[b] + s[threadIdx.x] - v;
}

// ---------------- scatter edges into src-sorted 16B records ----------------
__global__ void scatter_kernel(const int* __restrict__ ei, const int* __restrict__ e2g,
                               const void* __restrict__ fd, const int* __restrict__ starts,
                               int* __restrict__ ctr, int4* __restrict__ rec,
                               u16* __restrict__ fd2S, const int* __restrict__ flagp) {
    int bf = *flagp;
    int e = blockIdx.x * 256 + threadIdx.x;
    if (e >= N_EDGE) return;
    int s = ei[e];
    int pos = starts[s] + atomicAdd(&ctr[s], 1);
    float f0, f1, f2v;
    if (bf) {
        const u16* f = (const u16*)fd + (size_t)e * 3;
        f0 = b2f(f[0]); f1 = b2f(f[1]); f2v = b2f(f[2]);
    } else {
        const float* f = (const float*)fd + (size_t)e * 3;
        f0 = f[0]; f1 = f[1]; f2v = f[2];
    }
    int fd01 = (int)((unsigned)f2b(f0) | ((unsigned)f2b(f1) << 16));
    rec[pos] = make_int4(s, ei[N_EDGE + e], e2g[e], fd01);
    fd2S[pos] = f2b(f2v);
}

// ---------------- uv: U = h @ W1e[0:128], V = h @ W1e[128:256] ----------------
#define UVP 136
__global__ __launch_bounds__(256, 4) void uv_kernel(
    const u16* __restrict__ h, const u16* __restrict__ Wtp, const u16* __restrict__ Wmp,
    u16* __restrict__ U, u16* __restrict__ V) {
    __shared__ u16 sA[64 * UVP];
    int tid = threadIdx.x;
    int lane = tid & 63, w = tid >> 6;
    int r0 = blockIdx.x * 64;

    for (int i = tid; i < 1024; i += 256) {
        int row = i >> 4, c = i & 15;
        int gr = r0 + row; if (gr >= N_NODES) gr = N_NODES - 1;
        uint4 v = *(const uint4*)(h + (size_t)gr * H + c * 8);
        *(uint4*)(&sA[row * UVP + c * 8]) = v;
    }
    __syncthreads();

    const short8* Wt = (const short8*)Wtp;
    const short8* Wm = (const short8*)Wmp;
    int q8 = (lane >> 4) * 8;
    int mrow = lane & 15;
    int q = lane >> 4;

    floatx4 aU[4][2], aV[4][2];
    #pragma unroll
    for (int mt = 0; mt < 4; mt++) {
        aU[mt][0] = (floatx4){0,0,0,0}; aU[mt][1] = (floatx4){0,0,0,0};
        aV[mt][0] = (floatx4){0,0,0,0}; aV[mt][1] = (floatx4){0,0,0,0};
    }
    #pragma unroll
    for (int kt = 0; kt < 4; kt++) {
        short8 bu0 = Wt[(kt * 8 + 2 * w) * 64 + lane];
        short8 bu1 = Wt[(kt * 8 + 2 * w + 1) * 64 + lane];
        short8 bv0 = Wm[(kt * 8 + 2 * w) * 64 + lane];
        short8 bv1 = Wm[(kt * 8 + 2 * w + 1) * 64 + lane];
        #pragma unroll
        for (int mt = 0; mt < 4; mt++) {
            short8 a = *(const short8*)(&sA[(mt * 16 + mrow) * UVP + kt * 32 + q8]);
            aU[mt][0] = __builtin_amdgcn_mfma_f32_16x16x32_bf16(a, bu0, aU[mt][0], 0, 0, 0);
            aU[mt][1] = __builtin_amdgcn_mfma_f32_16x16x32_bf16(a, bu1, aU[mt][1], 0, 0, 0);
            aV[mt][0] = __builtin_amdgcn_mfma_f32_16x16x32_bf16(a, bv0, aV[mt][0], 0, 0, 0);
            aV[mt][1] = __builtin_amdgcn_mfma_f32_16x16x32_bf16(a, bv1, aV[mt][1], 0, 0, 0);
        }
    }
    #pragma unroll
    for (int mt = 0; mt < 4; mt++) {
        #pragma unroll
        for (int nt = 0; nt < 2; nt++) {
            int n = w * 32 + nt * 16 + mrow;
            #pragma unroll
            for (int r = 0; r < 4; r++) {
                int gr = r0 + mt * 16 + q * 4 + r;
                if (gr < N_NODES) {
                    U[(size_t)gr * H + n] = f2b(aU[mt][nt][r]);
                    V[(size_t)gr * H + n] = f2b(aV[mt][nt][r]);
                }
            }
        }
    }
}

// ---------------- fused edge (src-sorted): gather + silu -> layer2 GEMM -> segmented reduce ----------------
#define PP 136

__global__ __launch_bounds__(256, 6) void edge_kernel(
    const u16* __restrict__ U, const u16* __restrict__ V, const u16* __restrict__ LGb,
    const int4* __restrict__ rec, const u16* __restrict__ fd2S,
    const void* __restrict__ W1e,
    const u16* __restrict__ W2p, const void* __restrict__ bias2,
    float* __restrict__ agg, const int* __restrict__ flagp) {
    __shared__ __align__(16) u16 sP[64 * PP];
    __shared__ int sSrc[64], sDst[64], sG[64];
    __shared__ float sFd[192];
    __shared__ float sB2[128];

    int bf = *flagp;
    int tid = threadIdx.x;
    int lane = tid & 63, w = tid >> 6;
    int e0 = blockIdx.x * 64;

    if (tid < 64) {
        int4 r = rec[e0 + tid];
        sSrc[tid] = r.x; sDst[tid] = r.y; sG[tid] = r.z;
        sFd[tid * 3 + 0] = b2f((u16)((unsigned)r.w & 0xFFFF));
        sFd[tid * 3 + 1] = b2f((u16)((unsigned)r.w >> 16));
        sFd[tid * 3 + 2] = b2f(fd2S[e0 + tid]);
    }
    if (tid < 128) sB2[tid] = bf ? b2f(((const u16*)bias2)[tid]) : ((const float*)bias2)[tid];

    // Wfd = W1e rows 265..267, cols c8..c8+7 (fixed per thread)
    int c8 = (tid & 15) * 8;
    float wf[3][8];
    #pragma unroll
    for (int k = 0; k < 3; k++)
        #pragma unroll
        for (int j = 0; j < 8; j++)
            wf[k][j] = bf ? b2f(((const u16*)W1e)[(size_t)(265 + k) * H + c8 + j])
                          : ((const float*)W1e)[(size_t)(265 + k) * H + c8 + j];
    __syncthreads();

    // gather (uint4) + fd-term + silu -> sP
    for (int i = tid; i < 1024; i += 256) {
        int row = i >> 4;
        int s = sSrc[row], d = sDst[row], g = sG[row];
        uint4 uu = *(const uint4*)(U + (size_t)s * H + c8);
        uint4 vv = *(const uint4*)(V + (size_t)d * H + c8);
        uint4 gg = *(const uint4*)(LGb + (size_t)g * H + c8);
        float f0 = sFd[row * 3], f1 = sFd[row * 3 + 1], f2v = sFd[row * 3 + 2];
        u16 o[8];
        #pragma unroll
        for (int j = 0; j < 8; j++) {
            float val = get_bf(uu, j) + get_bf(vv, j) + get_bf(gg, j)
                      + f0 * wf[0][j] + f1 * wf[1][j] + f2v * wf[2][j];
            o[j] = f2b(silu_f(val));
        }
        uint4 packed;
        __builtin_memcpy(&packed, o, 16);
        *(uint4*)(&sP[row * PP + c8]) = packed;
    }
    __syncthreads();

    const short8* W2v = (const short8*)W2p;
    int q8 = (lane >> 4) * 8;
    int mrow = lane & 15;
    int q = lane >> 4;

    // layer 2: [64,128] @ [128,128]
    floatx4 acc2[4][2];
    #pragma unroll
    for (int mt = 0; mt < 4; mt++) {
        acc2[mt][0] = (floatx4){0,0,0,0};
        acc2[mt][1] = (floatx4){0,0,0,0};
    }
    #pragma unroll
    for (int kt = 0; kt < 4; kt++) {
        short8 bf0 = W2v[(kt * 8 + 2 * w) * 64 + lane];
        short8 bf1 = W2v[(kt * 8 + 2 * w + 1) * 64 + lane];
        #pragma unroll
        for (int mt = 0; mt < 4; mt++) {
            short8 a = *(const short8*)(&sP[(mt * 16 + mrow) * PP + kt * 32 + q8]);
            acc2[mt][0] = __builtin_amdgcn_mfma_f32_16x16x32_bf16(a, bf0, acc2[mt][0], 0, 0, 0);
            acc2[mt][1] = __builtin_amdgcn_mfma_f32_16x16x32_bf16(a, bf1, acc2[mt][1], 0, 0, 0);
        }
    }
    __syncthreads();   // all sP A-frag reads done; safe to overwrite

    // bias + silu -> back into sP (bf16, row-major)
    #pragma unroll
    for (int mt = 0; mt < 4; mt++) {
        #pragma unroll
        for (int nt = 0; nt < 2; nt++) {
            int n = w * 32 + nt * 16 + mrow;
            float bias = sB2[n];
            #pragma unroll
            for (int r = 0; r < 4; r++) {
                int row = mt * 16 + q * 4 + r;
                sP[row * PP + n] = f2b(silu_f(acc2[mt][nt][r] + bias));
            }
        }
    }
    __syncthreads();

    // segmented reduction over src-sorted rows: one atomic per (segment, col).
    // col = tid&127, half = tid>>7 -> wave-uniform src sequence (no divergence).
    int col = tid & 127;
    int half = tid >> 7;
    int base = half * 32;
    float acc = 0.f;
    int cur = sSrc[base];
    #pragma unroll 4
    for (int rr = 0; rr < 32; rr++) {
        int row = base + rr;
        int s = sSrc[row];
        if (s != cur) {
            atomicAdd(&agg[(size_t)cur * H + col], acc);
            acc = 0.f;
            cur = s;
        }
        acc += b2f(sP[row * PP + col]);
    }
    atomicAdd(&agg[(size_t)cur * H + col], acc);
}

// ---------------- node MLP + residual ----------------
#define NKP 264

__global__ __launch_bounds__(256, 4) void node_kernel(
    const u16* __restrict__ h, const float* __restrict__ agg, const int* __restrict__ cnt,
    const void* __restrict__ nf,
    const u16* __restrict__ W1p, const u16* __restrict__ W2p,
    const void* __restrict__ bias1, const void* __restrict__ bias2,
    void* __restrict__ out, const int* __restrict__ flagp) {
    __shared__ __align__(16) u16 sU[64 * NKP];
    __shared__ float sB1[128], sB2[128];
    u16* sA = sU;
    u16* sP = sU;

    int bf = *flagp;
    int tid = threadIdx.x;
    int lane = tid & 63, w = tid >> 6;
    int r0 = blockIdx.x * 64;

    if (tid < 128) sB1[tid] = bf ? b2f(((const u16*)bias1)[tid]) : ((const float*)bias1)[tid];
    else sB2[tid - 128] = bf ? b2f(((const u16*)bias2)[tid - 128]) : ((const float*)bias2)[tid - 128];

    for (int i = tid; i < 1024; i += 256) {
        int row = i >> 4, c = i & 15;
        int gr = r0 + row; if (gr >= N_NODES) gr = N_NODES - 1;
        uint4 v = *(const uint4*)(h + (size_t)gr * H + c * 8);
        *(uint4*)(&sA[row * NKP + c * 8]) = v;
    }
    for (int i = tid; i < 2048; i += 256) {
        int row = i >> 5, c = i & 31;
        int gr = r0 + row; if (gr >= N_NODES) gr = N_NODES - 1;
        int cn = cnt[gr];
        float sc = 1.0f / (float)(cn > 0 ? cn : 1);
        const float* ap = agg + (size_t)gr * H + c * 4;
        u16 vv[4];
        #pragma unroll
        for (int j = 0; j < 4; j++) vv[j] = f2b(ap[j] * sc);
        uint2 tmp;
        __builtin_memcpy(&tmp, vv, 8);
        *(uint2*)(&sA[row * NKP + 128 + c * 4]) = tmp;
    }
    __syncthreads();

    const short8* W1v = (const short8*)W1p;
    const short8* W2v = (const short8*)W2p;
    int q8 = (lane >> 4) * 8;
    int mrow = lane & 15;
    int q = lane >> 4;

    floatx4 acc[4][2];
    #pragma unroll
    for (int mt = 0; mt < 4; mt++) {
        acc[mt][0] = (floatx4){0,0,0,0};
        acc[mt][1] = (floatx4){0,0,0,0};
    }
    #pragma unroll
    for (int kt = 0; kt < 8; kt++) {
        short8 bf0 = W1v[(kt * 8 + 2 * w) * 64 + lane];
        short8 bf1 = W1v[(kt * 8 + 2 * w + 1) * 64 + lane];
        #pragma unroll
        for (int mt = 0; mt < 4; mt++) {
            short8 a = *(const short8*)(&sA[(mt * 16 + mrow) * NKP + kt * 32 + q8]);
            acc[mt][0] = __builtin_amdgcn_mfma_f32_16x16x32_bf16(a, bf0, acc[mt][0], 0, 0, 0);
            acc[mt][1] = __builtin_amdgcn_mfma_f32_16x16x32_bf16(a, bf1, acc[mt][1], 0, 0, 0);
        }
    }
    __syncthreads();

    #pragma unroll
    for (int mt = 0; mt < 4; mt++) {
        #pragma unroll
        for (int nt = 0; nt < 2; nt++) {
            int n = w * 32 + nt * 16 + mrow;
            float bias = sB1[n];
            #pragma unroll
            for (int r = 0; r < 4; r++) {
                int row = mt * 16 + q * 4 + r;
                sP[row * PP + n] = f2b(silu_f(acc[mt][nt][r] + bias));
            }
        }
    }
    __syncthreads();

    floatx4 acc2[4][2];
    #pragma unroll
    for (int mt = 0; mt < 4; mt++) {
        acc2[mt][0] = (floatx4){0,0,0,0};
        acc2[mt][1] = (floatx4){0,0,0,0};
    }
    #pragma unroll
    for (int kt = 0; kt < 4; kt++) {
        short8 bf0 = W2v[(kt * 8 + 2 * w) * 64 + lane];
        short8 bf1 = W2v[(kt * 8 + 2 * w + 1) * 64 + lane];
        #pragma unroll
        for (int mt = 0; mt < 4; mt++) {
            short8 a = *(const short8*)(&sP[(mt * 16 + mrow) * PP + kt * 32 + q8]);
            acc2[mt][0] = __builtin_amdgcn_mfma_f32_16x16x32_bf16(a, bf0, acc2[mt][0], 0, 0, 0);
            acc2[mt][1] = __builtin_amdgcn_mfma_f32_16x16x32_bf16(a, bf1, acc2[mt][1], 0, 0, 0);
        }
    }
    #pragma unroll
    for (int mt = 0; mt < 4; mt++) {
        #pragma unroll
        for (int nt = 0; nt < 2; nt++) {
            int n = w * 32 + nt * 16 + mrow;
            float bias = sB2[n];
            #pragma unroll
            for (int r = 0; r < 4; r++) {
                int row = mt * 16 + q * 4 + r;
                int gr = r0 + row;
                if (gr < N_NODES) {
                    float s = silu_f(acc2[mt][nt][r] + bias);
                    size_t idx = (size_t)gr * H + n;
                    float nv = bf ? b2f(((const u16*)nf)[idx]) : ((const float*)nf)[idx];
                    float o = nv + s;
                    if (bf) ((u16*)out)[idx] = f2b(o);
                    else ((float*)out)[idx] = o;
                }
            }
        }
    }
}

extern "C" void kernel_launch(void* const* d_in, const int* in_sizes, int n_in,
                              void* d_out, int out_size, void* d_ws, size_t ws_size,
                              hipStream_t stream) {
    const void* node_features = d_in[0];
    const void* lattices      = d_in[1];
    const int* edge_index     = (const int*)d_in[2];
    const int* edge2graph     = (const int*)d_in[3];
    const void* frac_diff     = d_in[4];
    const void* W1e = d_in[5];  const void* b1e = d_in[6];
    const void* W2e = d_in[7];  const void* b2e = d_in[8];
    const void* W1n = d_in[9];  const void* b1n = d_in[10];
    const void* W2n = d_in[11]; const void* b2n = d_in[12];
    const void* ln_g = d_in[13];
    const void* ln_b = d_in[14];

    char* ws = (char*)d_ws;
    size_t off = 0;
    float* agg = (float*)(ws + off);            off += (size_t)N_NODES * H * 4;   // 51.2 MB
    int*   cnt = (int*)(ws + off);              off += (size_t)N_NODES * 4;
    int*   ctr = (int*)(ws + off);              off += (size_t)N_NODES * 4;
    size_t zero_bytes = off;                    // agg + cnt + ctr
    int*   flag = (int*)(ws + off);             off += 16;
    u16*   h    = (u16*)(ws + off);             off += (size_t)N_NODES * H * 2;   // 25.6 MB
    u16*   LGb  = (u16*)(ws + off);             off += (size_t)N_GRAPH * H * 2;   // 1.28 MB
    u16*   W1tp = (u16*)(ws + off);             off += (size_t)128 * 128 * 2;
    u16*   W1mp = (u16*)(ws + off);             off += (size_t)128 * 128 * 2;
    u16*   W2p  = (u16*)(ws + off);             off += (size_t)128 * 128 * 2;
    u16*   W1np = (u16*)(ws + off);             off += (size_t)256 * 128 * 2;
    u16*   W2np = (u16*)(ws + off);             off += (size_t)128 * 128 * 2;
    int*   starts = (int*)(ws + off);           off += (size_t)N_NODES * 4;
    int*   bsum = (int*)(ws + off);             off += 2048;
    int*   boff = (int*)(ws + off);             off += 2048;
    int4*  rec  = (int4*)(ws + off);            off += (size_t)N_EDGE * 16;       // 16 MB
    u16*   fd2S = (u16*)(ws + off);             off += (size_t)N_EDGE * 2;        // 2 MB

    // U, V live in d_out (dead until node_kernel writes it).
    u16* U = (u16*)d_out;
    u16* V = (u16*)d_out + (size_t)N_NODES * H;

    hipMemsetAsync(agg, 0, zero_bytes, stream);

    probe_kernel<<<1, 256, 0, stream>>>((const unsigned*)node_features, flag);
    ln_kernel<<<(N_NODES + 3) / 4, 256, 0, stream>>>(node_features, ln_g, ln_b, h, flag);
    lg_kernel<<<(N_GRAPH * 64 + 255) / 256, 256, 0, stream>>>(lattices, W1e, b1e, LGb, flag);
    pack_kernel<<<(4 * 8 * 64 + 255) / 256, 256, 0, stream>>>(W1e, W1tp, 0, 268, 4, flag);
    pack_kernel<<<(4 * 8 * 64 + 255) / 256, 256, 0, stream>>>(W1e, W1mp, 128, 268, 4, flag);
    pack_kernel<<<(4 * 8 * 64 + 255) / 256, 256, 0, stream>>>(W2e, W2p, 0, 128, 4, flag);
    pack_kernel<<<(8 * 8 * 64 + 255) / 256, 256, 0, stream>>>(W1n, W1np, 0, 256, 8, flag);
    pack_kernel<<<(4 * 8 * 64 + 255) / 256, 256, 0, stream>>>(W2n, W2np, 0, 128, 4, flag);
    cnt_kernel<<<(N_EDGE + 255) / 256, 256, 0, stream>>>(edge_index, cnt);

    ps1_kernel<<<NBLK, 256, 0, stream>>>(cnt, bsum);
    ps2_kernel<<<1, 512, 0, stream>>>(bsum, boff);
    ps3_kernel<<<NBLK, 256, 0, stream>>>(cnt, boff, starts);
    scatter_kernel<<<(N_EDGE + 255) / 256, 256, 0, stream>>>(edge_index, edge2graph, frac_diff,
                                                             starts, ctr, rec, fd2S, flag);

    uv_kernel<<<(N_NODES + 63) / 64, 256, 0, stream>>>(h, W1tp, W1mp, U, V);
    edge_kernel<<<N_EDGE / 64, 256, 0, stream>>>(U, V, LGb, rec, fd2S, W1e,
                                                 W2p, b2e, agg, flag);
    node_kernel<<<(N_NODES + 63) / 64, 256, 0, stream>>>(h, agg, cnt, node_features,
                                                         W1np, W2np, b1n, b2n, d_out, flag);
}

// Round 7
// 467.623 us; speedup vs baseline: 1.6551x; 1.3150x over previous
//
#include <hip/hip_runtime.h>
#include <stdint.h>

// R7: VALU-diet on the R6 structure. silu via fmed3+exp2+rcp; packed bf16
// converts (v_cvt_pk_bf16_f32); vectorized Wfd loads; LN fused into uv (lnuv)
// with LDS-bounce vector stores; node LDS-bounce store; 5 pack kernels -> 1.

#define N_NODES 100000
#define N_GRAPH 5000
#define N_EDGE  1000000
#define H 128
#define NBLK 391   // ceil(N_NODES/256)

typedef unsigned short u16;
typedef __attribute__((ext_vector_type(8))) short short8;
typedef __attribute__((ext_vector_type(4))) float floatx4;

__device__ inline float b2f(u16 x) {
    unsigned u = ((unsigned)x) << 16;
    return __uint_as_float(u);
}
__device__ inline u16 f2b(float f) {
    unsigned u = __float_as_uint(f);
    unsigned r = (u + 0x7FFFu + ((u >> 16) & 1u)) >> 16;  // RNE
    return (u16)r;
}
__device__ inline unsigned cvt_pk_bf16(float lo, float hi) {
    unsigned r;
    asm("v_cvt_pk_bf16_f32 %0, %1, %2" : "=v"(r) : "v"(lo), "v"(hi));
    return r;
}
__device__ inline float silu_f(float x) {
    x = __builtin_amdgcn_fmed3f(x, -30.f, 30.f);
    float e = __builtin_amdgcn_exp2f(x * -1.442695040888963f);
    return x * __builtin_amdgcn_rcpf(1.f + e);
}
__device__ inline float get_bf(const uint4& v, int j) {
    unsigned w = ((const unsigned*)&v)[j >> 1];
    return b2f((u16)(w >> (16 * (j & 1))));
}

// ---------------- dtype probe: flag=1 if inputs are bf16, 0 if fp32 ----------------
__global__ void probe_kernel(const unsigned* __restrict__ nf_raw, int* __restrict__ flag) {
    __shared__ int cnt_s;
    if (threadIdx.x == 0) cnt_s = 0;
    __syncthreads();
    unsigned u = nf_raw[threadIdx.x];
    unsigned e2 = (u >> 7) & 0xFF;
    int in_range = (e2 >= 90 && e2 <= 160) ? 1 : 0;
    atomicAdd(&cnt_s, in_range);
    __syncthreads();
    if (threadIdx.x == 0) *flag = (cnt_s >= 128) ? 1 : 0;
}

// ---------------- LG[g][c] = b1e[c] + sum_ij ltl(g)_ij * W1e[256+ij][c] ----------------
__global__ void lg_kernel(const void* __restrict__ lat, const void* __restrict__ W1e,
                          const void* __restrict__ b1e, u16* __restrict__ LGb,
                          const int* __restrict__ flagp) {
    int bf = *flagp;
    int t = blockIdx.x * 256 + threadIdx.x;
    if (t >= N_GRAPH * 64) return;
    int g = t >> 6, cp = (t & 63) * 2;
    float L[9];
    #pragma unroll
    for (int k = 0; k < 9; k++)
        L[k] = bf ? b2f(((const u16*)lat)[g * 9 + k]) : ((const float*)lat)[g * 9 + k];
    float a0 = bf ? b2f(((const u16*)b1e)[cp])     : ((const float*)b1e)[cp];
    float a1 = bf ? b2f(((const u16*)b1e)[cp + 1]) : ((const float*)b1e)[cp + 1];
    #pragma unroll
    for (int i = 0; i < 3; i++) {
        #pragma unroll
        for (int j = 0; j < 3; j++) {
            float lt = L[i*3] * L[j*3] + L[i*3+1] * L[j*3+1] + L[i*3+2] * L[j*3+2];
            int r = 256 + i * 3 + j;
            float w0 = bf ? b2f(((const u16*)W1e)[(size_t)r * H + cp])     : ((const float*)W1e)[(size_t)r * H + cp];
            float w1 = bf ? b2f(((const u16*)W1e)[(size_t)r * H + cp + 1]) : ((const float*)W1e)[(size_t)r * H + cp + 1];
            a0 += lt * w0;
            a1 += lt * w1;
        }
    }
    LGb[(size_t)g * H + cp] = f2b(a0);
    LGb[(size_t)g * H + cp + 1] = f2b(a1);
}

// ---------------- pack all 5 weight matrices -> MFMA B-fragment layout (one kernel) ----------------
__global__ void packall_kernel(const void* __restrict__ W1e, const void* __restrict__ W2e,
                               const void* __restrict__ W1n, const void* __restrict__ W2n,
                               u16* __restrict__ W1tp, u16* __restrict__ W1mp, u16* __restrict__ W2p,
                               u16* __restrict__ W1np, u16* __restrict__ W2np,
                               const int* __restrict__ flagp) {
    int bf = *flagp;
    int blk = blockIdx.x;
    const void* W; u16* out; int k0, Ktot, base;
    if (blk < 8)       { W = W1e; out = W1tp; k0 = 0;   Ktot = 268; base = 0; }
    else if (blk < 16) { W = W1e; out = W1mp; k0 = 128; Ktot = 268; base = 8; }
    else if (blk < 24) { W = W2e; out = W2p;  k0 = 0;   Ktot = 128; base = 16; }
    else if (blk < 40) { W = W1n; out = W1np; k0 = 0;   Ktot = 256; base = 24; }
    else               { W = W2n; out = W2np; k0 = 0;   Ktot = 128; base = 40; }
    int t = (blk - base) * 256 + threadIdx.x;
    int lane = t & 63, nt = (t >> 6) & 7, kt = t >> 9;
    int n = nt * 16 + (lane & 15);
    int kbase = k0 + kt * 32 + ((lane >> 4) << 3);
    u16 vals[8];
    #pragma unroll
    for (int j = 0; j < 8; j++) {
        int k = kbase + j;
        if (k >= Ktot) vals[j] = 0;
        else if (bf) vals[j] = ((const u16*)W)[(size_t)k * H + n];
        else vals[j] = f2b(((const float*)W)[(size_t)k * H + n]);
    }
    uint4 tmp;
    __builtin_memcpy(&tmp, vals, 16);
    *(uint4*)(out + (size_t)t * 8) = tmp;
}

// ---------------- degree counts over edge_index[0] ----------------
__global__ void cnt_kernel(const int* __restrict__ ei, int* __restrict__ cnt) {
    int e = blockIdx.x * 256 + threadIdx.x;
    if (e < N_EDGE) atomicAdd(&cnt[ei[e]], 1);
}

// ---------------- prefix-scan of degrees -> starts ----------------
__global__ void ps1_kernel(const int* __restrict__ cnt, int* __restrict__ bsum) {
    __shared__ int s[256];
    int i = blockIdx.x * 256 + threadIdx.x;
    s[threadIdx.x] = (i < N_NODES) ? cnt[i] : 0;
    __syncthreads();
    for (int off = 128; off >= 1; off >>= 1) {
        if (threadIdx.x < off) s[threadIdx.x] += s[threadIdx.x + off];
        __syncthreads();
    }
    if (threadIdx.x == 0) bsum[blockIdx.x] = s[0];
}

__global__ void ps2_kernel(const int* __restrict__ bsum, int* __restrict__ boff) {
    __shared__ int s[512];
    int t = threadIdx.x;
    int v = (t < NBLK) ? bsum[t] : 0;
    s[t] = v;
    __syncthreads();
    for (int off = 1; off < 512; off <<= 1) {
        int add = (t >= off) ? s[t - off] : 0;
        __syncthreads();
        s[t] += add;
        __syncthreads();
    }
    if (t < NBLK) boff[t] = s[t] - v;   // exclusive
}

__global__ void ps3_kernel(const int* __restrict__ cnt, const int* __restrict__ boff,
                           int* __restrict__ starts) {
    __shared__ int s[256];
    int b = blockIdx.x;
    int i = b * 256 + threadIdx.x;
    int v = (i < N_NODES) ? cnt[i] : 0;
    s[threadIdx.x] = v;
    __syncthreads();
    for (int off = 1; off < 256; off <<= 1) {
        int add = (threadIdx.x >= off) ? s[threadIdx.x - off] : 0;
        __syncthreads();
        s[threadIdx.x] += add;
        __syncthreads();
    }
    if (i < N_NODES) starts[i] = boff[b] + s[threadIdx.x] - v;
}

// ---------------- scatter edges into src-sorted 16B records ----------------
__global__ void scatter_kernel(const int* __restrict__ ei, const int* __restrict__ e2g,
                               const void* __restrict__ fd, const int* __restrict__ starts,
                               int* __restrict__ ctr, int4* __restrict__ rec,
                               u16* __restrict__ fd2S, const int* __restrict__ flagp) {
    int bf = *flagp;
    int e = blockIdx.x * 256 + threadIdx.x;
    if (e >= N_EDGE) return;
    int s = ei[e];
    int pos = starts[s] + atomicAdd(&ctr[s], 1);
    float f0, f1, f2v;
    if (bf) {
        const u16* f = (const u16*)fd + (size_t)e * 3;
        f0 = b2f(f[0]); f1 = b2f(f[1]); f2v = b2f(f[2]);
    } else {
        const float* f = (const float*)fd + (size_t)e * 3;
        f0 = f[0]; f1 = f[1]; f2v = f[2];
    }
    int fd01 = (int)((unsigned)f2b(f0) | ((unsigned)f2b(f1) << 16));
    rec[pos] = make_int4(s, ei[N_EDGE + e], e2g[e], fd01);
    fd2S[pos] = f2b(f2v);
}

// ---------------- lnuv: LN(node_features) -> h  AND  U = h@W1e[0:128], V = h@W1e[128:256] ----------------
#define UVP 136
__global__ __launch_bounds__(256, 3) void lnuv_kernel(
    const void* __restrict__ nf, const void* __restrict__ lng, const void* __restrict__ lnb,
    const u16* __restrict__ Wtp, const u16* __restrict__ Wmp,
    u16* __restrict__ h, u16* __restrict__ U, u16* __restrict__ V,
    const int* __restrict__ flagp) {
    __shared__ __align__(16) u16 sA[64 * UVP];
    int bf = *flagp;
    int tid = threadIdx.x;
    int lane = tid & 63, w = tid >> 6;
    int r0 = blockIdx.x * 64;

    // ---- LN stage: one (row, quarter) per thread ----
    {
        int row = tid >> 2, part = tid & 3;
        int gr = r0 + row;
        bool valid = gr < N_NODES;
        int grc = valid ? gr : N_NODES - 1;
        float x[32];
        if (bf) {
            const u16* p = (const u16*)nf + (size_t)grc * H + part * 32;
            #pragma unroll
            for (int j8 = 0; j8 < 4; j8++) {
                uint4 v = *(const uint4*)(p + j8 * 8);
                #pragma unroll
                for (int j = 0; j < 8; j++) x[j8 * 8 + j] = get_bf(v, j);
            }
        } else {
            const float* p = (const float*)nf + (size_t)grc * H + part * 32;
            #pragma unroll
            for (int j4 = 0; j4 < 8; j4++) {
                float4 v = *(const float4*)(p + j4 * 4);
                x[j4*4] = v.x; x[j4*4+1] = v.y; x[j4*4+2] = v.z; x[j4*4+3] = v.w;
            }
        }
        float s1 = 0.f, s2 = 0.f;
        #pragma unroll
        for (int j = 0; j < 32; j++) { s1 += x[j]; s2 += x[j] * x[j]; }
        s1 += __shfl_xor(s1, 1, 64); s2 += __shfl_xor(s2, 1, 64);
        s1 += __shfl_xor(s1, 2, 64); s2 += __shfl_xor(s2, 2, 64);
        float mu = s1 * (1.0f / H);
        float var = s2 * (1.0f / H) - mu * mu;
        float rs = rsqrtf(var + 1e-5f);
        unsigned pk[16];
        if (bf) {
            const u16* gp = (const u16*)lng + part * 32;
            const u16* bp = (const u16*)lnb + part * 32;
            #pragma unroll
            for (int j8 = 0; j8 < 4; j8++) {
                uint4 gv = *(const uint4*)(gp + j8 * 8);
                uint4 bv = *(const uint4*)(bp + j8 * 8);
                #pragma unroll
                for (int j2 = 0; j2 < 4; j2++) {
                    int j = j8 * 8 + j2 * 2;
                    float y0 = (x[j] - mu) * rs * get_bf(gv, j2*2)     + get_bf(bv, j2*2);
                    float y1 = (x[j+1] - mu) * rs * get_bf(gv, j2*2+1) + get_bf(bv, j2*2+1);
                    pk[j >> 1] = cvt_pk_bf16(y0, y1);
                }
            }
        } else {
            const float* gp = (const float*)lng + part * 32;
            const float* bp = (const float*)lnb + part * 32;
            #pragma unroll
            for (int j4 = 0; j4 < 8; j4++) {
                float4 gv = *(const float4*)(gp + j4 * 4);
                float4 bv = *(const float4*)(bp + j4 * 4);
                int j = j4 * 4;
                float y0 = (x[j]   - mu) * rs * gv.x + bv.x;
                float y1 = (x[j+1] - mu) * rs * gv.y + bv.y;
                float y2 = (x[j+2] - mu) * rs * gv.z + bv.z;
                float y3 = (x[j+3] - mu) * rs * gv.w + bv.w;
                pk[j >> 1]       = cvt_pk_bf16(y0, y1);
                pk[(j >> 1) + 1] = cvt_pk_bf16(y2, y3);
            }
        }
        uint4* d = (uint4*)&sA[row * UVP + part * 32];
        #pragma unroll
        for (int j4 = 0; j4 < 4; j4++) {
            uint4 t4 = make_uint4(pk[j4*4], pk[j4*4+1], pk[j4*4+2], pk[j4*4+3]);
            d[j4] = t4;
            if (valid) *((uint4*)(h + (size_t)gr * H + part * 32) + j4) = t4;
        }
    }
    __syncthreads();

    const short8* Wt = (const short8*)Wtp;
    const short8* Wm = (const short8*)Wmp;
    int q8 = (lane >> 4) * 8;
    int mrow = lane & 15;
    int q = lane >> 4;

    floatx4 aU[4][2], aV[4][2];
    #pragma unroll
    for (int mt = 0; mt < 4; mt++) {
        aU[mt][0] = (floatx4){0,0,0,0}; aU[mt][1] = (floatx4){0,0,0,0};
        aV[mt][0] = (floatx4){0,0,0,0}; aV[mt][1] = (floatx4){0,0,0,0};
    }
    #pragma unroll
    for (int kt = 0; kt < 4; kt++) {
        short8 bu0 = Wt[(kt * 8 + 2 * w) * 64 + lane];
        short8 bu1 = Wt[(kt * 8 + 2 * w + 1) * 64 + lane];
        short8 bv0 = Wm[(kt * 8 + 2 * w) * 64 + lane];
        short8 bv1 = Wm[(kt * 8 + 2 * w + 1) * 64 + lane];
        #pragma unroll
        for (int mt = 0; mt < 4; mt++) {
            short8 a = *(const short8*)(&sA[(mt * 16 + mrow) * UVP + kt * 32 + q8]);
            aU[mt][0] = __builtin_amdgcn_mfma_f32_16x16x32_bf16(a, bu0, aU[mt][0], 0, 0, 0);
            aU[mt][1] = __builtin_amdgcn_mfma_f32_16x16x32_bf16(a, bu1, aU[mt][1], 0, 0, 0);
            aV[mt][0] = __builtin_amdgcn_mfma_f32_16x16x32_bf16(a, bv0, aV[mt][0], 0, 0, 0);
            aV[mt][1] = __builtin_amdgcn_mfma_f32_16x16x32_bf16(a, bv1, aV[mt][1], 0, 0, 0);
        }
    }
    __syncthreads();   // sA free; LDS-bounce U then V for vector stores

    #pragma unroll
    for (int mt = 0; mt < 4; mt++)
        #pragma unroll
        for (int nt = 0; nt < 2; nt++) {
            int n = w * 32 + nt * 16 + mrow;
            #pragma unroll
            for (int r = 0; r < 4; r++)
                sA[(mt * 16 + q * 4 + r) * UVP + n] = f2b(aU[mt][nt][r]);
        }
    __syncthreads();
    for (int i = tid; i < 1024; i += 256) {
        int row = i >> 4, c = i & 15;
        int gr = r0 + row;
        if (gr < N_NODES)
            *(uint4*)(U + (size_t)gr * H + c * 8) = *(const uint4*)(&sA[row * UVP + c * 8]);
    }
    __syncthreads();
    #pragma unroll
    for (int mt = 0; mt < 4; mt++)
        #pragma unroll
        for (int nt = 0; nt < 2; nt++) {
            int n = w * 32 + nt * 16 + mrow;
            #pragma unroll
            for (int r = 0; r < 4; r++)
                sA[(mt * 16 + q * 4 + r) * UVP + n] = f2b(aV[mt][nt][r]);
        }
    __syncthreads();
    for (int i = tid; i < 1024; i += 256) {
        int row = i >> 4, c = i & 15;
        int gr = r0 + row;
        if (gr < N_NODES)
            *(uint4*)(V + (size_t)gr * H + c * 8) = *(const uint4*)(&sA[row * UVP + c * 8]);
    }
}

// ---------------- fused edge (src-sorted): gather + silu -> layer2 GEMM -> segmented reduce ----------------
#define PP 136

__global__ __launch_bounds__(256, 6) void edge_kernel(
    const u16* __restrict__ U, const u16* __restrict__ V, const u16* __restrict__ LGb,
    const int4* __restrict__ rec, const u16* __restrict__ fd2S,
    const void* __restrict__ W1e,
    const u16* __restrict__ W2p, const void* __restrict__ bias2,
    float* __restrict__ agg, const int* __restrict__ flagp) {
    __shared__ __align__(16) u16 sP[64 * PP];
    __shared__ int sSrc[64], sDst[64], sG[64];
    __shared__ float sFd[192];
    __shared__ float sB2[128];

    int bf = *flagp;
    int tid = threadIdx.x;
    int lane = tid & 63, w = tid >> 6;
    int e0 = blockIdx.x * 64;

    if (tid < 64) {
        int4 r = rec[e0 + tid];
        sSrc[tid] = r.x; sDst[tid] = r.y; sG[tid] = r.z;
        sFd[tid * 3 + 0] = b2f((u16)((unsigned)r.w & 0xFFFF));
        sFd[tid * 3 + 1] = b2f((u16)((unsigned)r.w >> 16));
        sFd[tid * 3 + 2] = b2f(fd2S[e0 + tid]);
    }
    if (tid < 128) sB2[tid] = bf ? b2f(((const u16*)bias2)[tid]) : ((const float*)bias2)[tid];

    // Wfd = W1e rows 265..267, cols c8..c8+7 (fixed per thread) — vector loads
    int c8 = (tid & 15) * 8;
    float wf[3][8];
    if (bf) {
        #pragma unroll
        for (int k = 0; k < 3; k++) {
            uint4 wv = *(const uint4*)((const u16*)W1e + (size_t)(265 + k) * H + c8);
            #pragma unroll
            for (int j = 0; j < 8; j++) wf[k][j] = get_bf(wv, j);
        }
    } else {
        #pragma unroll
        for (int k = 0; k < 3; k++) {
            const float* wr = (const float*)W1e + (size_t)(265 + k) * H + c8;
            float4 a4 = *(const float4*)wr;
            float4 b4 = *(const float4*)(wr + 4);
            wf[k][0] = a4.x; wf[k][1] = a4.y; wf[k][2] = a4.z; wf[k][3] = a4.w;
            wf[k][4] = b4.x; wf[k][5] = b4.y; wf[k][6] = b4.z; wf[k][7] = b4.w;
        }
    }
    __syncthreads();

    // gather (uint4) + fd-term + silu -> sP (packed converts)
    for (int i = tid; i < 1024; i += 256) {
        int row = i >> 4;
        int s = sSrc[row], d = sDst[row], g = sG[row];
        uint4 uu = *(const uint4*)(U + (size_t)s * H + c8);
        uint4 vv = *(const uint4*)(V + (size_t)d * H + c8);
        uint4 gg = *(const uint4*)(LGb + (size_t)g * H + c8);
        float f0 = sFd[row * 3], f1 = sFd[row * 3 + 1], f2v = sFd[row * 3 + 2];
        float y[8];
        #pragma unroll
        for (int j = 0; j < 8; j++) {
            float val = get_bf(uu, j) + get_bf(vv, j) + get_bf(gg, j)
                      + f0 * wf[0][j] + f1 * wf[1][j] + f2v * wf[2][j];
            y[j] = silu_f(val);
        }
        uint4 packed = make_uint4(cvt_pk_bf16(y[0], y[1]), cvt_pk_bf16(y[2], y[3]),
                                  cvt_pk_bf16(y[4], y[5]), cvt_pk_bf16(y[6], y[7]));
        *(uint4*)(&sP[row * PP + c8]) = packed;
    }
    __syncthreads();

    const short8* W2v = (const short8*)W2p;
    int q8 = (lane >> 4) * 8;
    int mrow = lane & 15;
    int q = lane >> 4;

    // layer 2: [64,128] @ [128,128]
    floatx4 acc2[4][2];
    #pragma unroll
    for (int mt = 0; mt < 4; mt++) {
        acc2[mt][0] = (floatx4){0,0,0,0};
        acc2[mt][1] = (floatx4){0,0,0,0};
    }
    #pragma unroll
    for (int kt = 0; kt < 4; kt++) {
        short8 bf0 = W2v[(kt * 8 + 2 * w) * 64 + lane];
        short8 bf1 = W2v[(kt * 8 + 2 * w + 1) * 64 + lane];
        #pragma unroll
        for (int mt = 0; mt < 4; mt++) {
            short8 a = *(const short8*)(&sP[(mt * 16 + mrow) * PP + kt * 32 + q8]);
            acc2[mt][0] = __builtin_amdgcn_mfma_f32_16x16x32_bf16(a, bf0, acc2[mt][0], 0, 0, 0);
            acc2[mt][1] = __builtin_amdgcn_mfma_f32_16x16x32_bf16(a, bf1, acc2[mt][1], 0, 0, 0);
        }
    }
    __syncthreads();   // all sP A-frag reads done; safe to overwrite

    // bias + silu -> back into sP (bf16, row-major)
    #pragma unroll
    for (int mt = 0; mt < 4; mt++) {
        #pragma unroll
        for (int nt = 0; nt < 2; nt++) {
            int n = w * 32 + nt * 16 + mrow;
            float bias = sB2[n];
            #pragma unroll
            for (int r = 0; r < 4; r++) {
                int row = mt * 16 + q * 4 + r;
                sP[row * PP + n] = f2b(silu_f(acc2[mt][nt][r] + bias));
            }
        }
    }
    __syncthreads();

    // segmented reduction over src-sorted rows: one atomic per (segment, col).
    int col = tid & 127;
    int half = tid >> 7;
    int base = half * 32;
    float acc = 0.f;
    int cur = sSrc[base];
    #pragma unroll 4
    for (int rr = 0; rr < 32; rr++) {
        int row = base + rr;
        int s = sSrc[row];
        if (s != cur) {
            atomicAdd(&agg[(size_t)cur * H + col], acc);
            acc = 0.f;
            cur = s;
        }
        acc += b2f(sP[row * PP + col]);
    }
    atomicAdd(&agg[(size_t)cur * H + col], acc);
}

// ---------------- node MLP + residual ----------------
#define NKP 264

__global__ __launch_bounds__(256, 4) void node_kernel(
    const u16* __restrict__ h, const float* __restrict__ agg, const int* __restrict__ cnt,
    const void* __restrict__ nf,
    const u16* __restrict__ W1p, const u16* __restrict__ W2p,
    const void* __restrict__ bias1, const void* __restrict__ bias2,
    void* __restrict__ out, const int* __restrict__ flagp) {
    __shared__ __align__(16) u16 sU[64 * NKP];
    __shared__ float sB1[128], sB2[128];
    u16* sA = sU;
    u16* sP = sU;

    int bf = *flagp;
    int tid = threadIdx.x;
    int lane = tid & 63, w = tid >> 6;
    int r0 = blockIdx.x * 64;

    if (tid < 128) sB1[tid] = bf ? b2f(((const u16*)bias1)[tid]) : ((const float*)bias1)[tid];
    else sB2[tid - 128] = bf ? b2f(((const u16*)bias2)[tid - 128]) : ((const float*)bias2)[tid - 128];

    // stage h rows (cols 0..127)
    for (int i = tid; i < 1024; i += 256) {
        int row = i >> 4, c = i & 15;
        int gr = r0 + row; if (gr >= N_NODES) gr = N_NODES - 1;
        uint4 v = *(const uint4*)(h + (size_t)gr * H + c * 8);
        *(uint4*)(&sA[row * NKP + c * 8]) = v;
    }
    // stage agg/cnt rows (cols 128..255), fp32 -> bf16 with packed converts
    for (int i = tid; i < 1024; i += 256) {
        int row = i >> 4, c = i & 15;
        int gr = r0 + row; if (gr >= N_NODES) gr = N_NODES - 1;
        int cn = cnt[gr];
        float sc = 1.0f / (float)(cn > 0 ? cn : 1);
        const float* ap = agg + (size_t)gr * H + c * 8;
        float4 a4 = *(const float4*)ap;
        float4 b4 = *(const float4*)(ap + 4);
        uint4 packed = make_uint4(cvt_pk_bf16(a4.x * sc, a4.y * sc), cvt_pk_bf16(a4.z * sc, a4.w * sc),
                                  cvt_pk_bf16(b4.x * sc, b4.y * sc), cvt_pk_bf16(b4.z * sc, b4.w * sc));
        *(uint4*)(&sA[row * NKP + 128 + c * 8]) = packed;
    }
    __syncthreads();

    const short8* W1v = (const short8*)W1p;
    const short8* W2v = (const short8*)W2p;
    int q8 = (lane >> 4) * 8;
    int mrow = lane & 15;
    int q = lane >> 4;

    floatx4 acc[4][2];
    #pragma unroll
    for (int mt = 0; mt < 4; mt++) {
        acc[mt][0] = (floatx4){0,0,0,0};
        acc[mt][1] = (floatx4){0,0,0,0};
    }
    #pragma unroll
    for (int kt = 0; kt < 8; kt++) {
        short8 bf0 = W1v[(kt * 8 + 2 * w) * 64 + lane];
        short8 bf1 = W1v[(kt * 8 + 2 * w + 1) * 64 + lane];
        #pragma unroll
        for (int mt = 0; mt < 4; mt++) {
            short8 a = *(const short8*)(&sA[(mt * 16 + mrow) * NKP + kt * 32 + q8]);
            acc[mt][0] = __builtin_amdgcn_mfma_f32_16x16x32_bf16(a, bf0, acc[mt][0], 0, 0, 0);
            acc[mt][1] = __builtin_amdgcn_mfma_f32_16x16x32_bf16(a, bf1, acc[mt][1], 0, 0, 0);
        }
    }
    __syncthreads();

    #pragma unroll
    for (int mt = 0; mt < 4; mt++) {
        #pragma unroll
        for (int nt = 0; nt < 2; nt++) {
            int n = w * 32 + nt * 16 + mrow;
            float bias = sB1[n];
            #pragma unroll
            for (int r = 0; r < 4; r++) {
                int row = mt * 16 + q * 4 + r;
                sP[row * PP + n] = f2b(silu_f(acc[mt][nt][r] + bias));
            }
        }
    }
    __syncthreads();

    floatx4 acc2[4][2];
    #pragma unroll
    for (int mt = 0; mt < 4; mt++) {
        acc2[mt][0] = (floatx4){0,0,0,0};
        acc2[mt][1] = (floatx4){0,0,0,0};
    }
    #pragma unroll
    for (int kt = 0; kt < 4; kt++) {
        short8 bf0 = W2v[(kt * 8 + 2 * w) * 64 + lane];
        short8 bf1 = W2v[(kt * 8 + 2 * w + 1) * 64 + lane];
        #pragma unroll
        for (int mt = 0; mt < 4; mt++) {
            short8 a = *(const short8*)(&sP[(mt * 16 + mrow) * PP + kt * 32 + q8]);
            acc2[mt][0] = __builtin_amdgcn_mfma_f32_16x16x32_bf16(a, bf0, acc2[mt][0], 0, 0, 0);
            acc2[mt][1] = __builtin_amdgcn_mfma_f32_16x16x32_bf16(a, bf1, acc2[mt][1], 0, 0, 0);
        }
    }
    __syncthreads();   // sP free again; LDS-bounce for vector out stores

    #pragma unroll
    for (int mt = 0; mt < 4; mt++) {
        #pragma unroll
        for (int nt = 0; nt < 2; nt++) {
            int n = w * 32 + nt * 16 + mrow;
            float bias = sB2[n];
            #pragma unroll
            for (int r = 0; r < 4; r++) {
                int row = mt * 16 + q * 4 + r;
                sP[row * PP + n] = f2b(silu_f(acc2[mt][nt][r] + bias));
            }
        }
    }
    __syncthreads();

    // vectorized residual add + store
    for (int i = tid; i < 1024; i += 256) {
        int row = i >> 4, c = i & 15;
        int gr = r0 + row;
        if (gr >= N_NODES) continue;
        uint4 sv = *(const uint4*)(&sP[row * PP + c * 8]);
        size_t idx = (size_t)gr * H + c * 8;
        if (bf) {
            uint4 nv = *(const uint4*)((const u16*)nf + idx);
            float o[8];
            #pragma unroll
            for (int j = 0; j < 8; j++) o[j] = get_bf(nv, j) + get_bf(sv, j);
            uint4 packed = make_uint4(cvt_pk_bf16(o[0], o[1]), cvt_pk_bf16(o[2], o[3]),
                                      cvt_pk_bf16(o[4], o[5]), cvt_pk_bf16(o[6], o[7]));
            *(uint4*)((u16*)out + idx) = packed;
        } else {
            const float* np = (const float*)nf + idx;
            float4 a4 = *(const float4*)np;
            float4 b4 = *(const float4*)(np + 4);
            a4.x += get_bf(sv, 0); a4.y += get_bf(sv, 1); a4.z += get_bf(sv, 2); a4.w += get_bf(sv, 3);
            b4.x += get_bf(sv, 4); b4.y += get_bf(sv, 5); b4.z += get_bf(sv, 6); b4.w += get_bf(sv, 7);
            float* op = (float*)out + idx;
            *(float4*)op = a4;
            *(float4*)(op + 4) = b4;
        }
    }
}

extern "C" void kernel_launch(void* const* d_in, const int* in_sizes, int n_in,
                              void* d_out, int out_size, void* d_ws, size_t ws_size,
                              hipStream_t stream) {
    const void* node_features = d_in[0];
    const void* lattices      = d_in[1];
    const int* edge_index     = (const int*)d_in[2];
    const int* edge2graph     = (const int*)d_in[3];
    const void* frac_diff     = d_in[4];
    const void* W1e = d_in[5];  const void* b1e = d_in[6];
    const void* W2e = d_in[7];  const void* b2e = d_in[8];
    const void* W1n = d_in[9];  const void* b1n = d_in[10];
    const void* W2n = d_in[11]; const void* b2n = d_in[12];
    const void* ln_g = d_in[13];
    const void* ln_b = d_in[14];

    char* ws = (char*)d_ws;
    size_t off = 0;
    float* agg = (float*)(ws + off);            off += (size_t)N_NODES * H * 4;   // 51.2 MB
    int*   cnt = (int*)(ws + off);              off += (size_t)N_NODES * 4;
    int*   ctr = (int*)(ws + off);              off += (size_t)N_NODES * 4;
    size_t zero_bytes = off;                    // agg + cnt + ctr
    int*   flag = (int*)(ws + off);             off += 16;
    u16*   h    = (u16*)(ws + off);             off += (size_t)N_NODES * H * 2;   // 25.6 MB
    u16*   LGb  = (u16*)(ws + off);             off += (size_t)N_GRAPH * H * 2;   // 1.28 MB
    u16*   W1tp = (u16*)(ws + off);             off += (size_t)128 * 128 * 2;
    u16*   W1mp = (u16*)(ws + off);             off += (size_t)128 * 128 * 2;
    u16*   W2p  = (u16*)(ws + off);             off += (size_t)128 * 128 * 2;
    u16*   W1np = (u16*)(ws + off);             off += (size_t)256 * 128 * 2;
    u16*   W2np = (u16*)(ws + off);             off += (size_t)128 * 128 * 2;
    int*   starts = (int*)(ws + off);           off += (size_t)N_NODES * 4;
    int*   bsum = (int*)(ws + off);             off += 2048;
    int*   boff = (int*)(ws + off);             off += 2048;
    int4*  rec  = (int4*)(ws + off);            off += (size_t)N_EDGE * 16;       // 16 MB
    u16*   fd2S = (u16*)(ws + off);             off += (size_t)N_EDGE * 2;        // 2 MB

    // U, V live in d_out (dead until node_kernel writes it).
    u16* U = (u16*)d_out;
    u16* V = (u16*)d_out + (size_t)N_NODES * H;

    hipMemsetAsync(agg, 0, zero_bytes, stream);

    probe_kernel<<<1, 256, 0, stream>>>((const unsigned*)node_features, flag);
    lg_kernel<<<(N_GRAPH * 64 + 255) / 256, 256, 0, stream>>>(lattices, W1e, b1e, LGb, flag);
    packall_kernel<<<48, 256, 0, stream>>>(W1e, W2e, W1n, W2n, W1tp, W1mp, W2p, W1np, W2np, flag);
    cnt_kernel<<<(N_EDGE + 255) / 256, 256, 0, stream>>>(edge_index, cnt);
    ps1_kernel<<<NBLK, 256, 0, stream>>>(cnt, bsum);
    ps2_kernel<<<1, 512, 0, stream>>>(bsum, boff);
    ps3_kernel<<<NBLK, 256, 0, stream>>>(cnt, boff, starts);
    scatter_kernel<<<(N_EDGE + 255) / 256, 256, 0, stream>>>(edge_index, edge2graph, frac_diff,
                                                             starts, ctr, rec, fd2S, flag);
    lnuv_kernel<<<(N_NODES + 63) / 64, 256, 0, stream>>>(node_features, ln_g, ln_b,
                                                         W1tp, W1mp, h, U, V, flag);
    edge_kernel<<<N_EDGE / 64, 256, 0, stream>>>(U, V, LGb, rec, fd2S, W1e,
                                                 W2p, b2e, agg, flag);
    node_kernel<<<(N_NODES + 63) / 64, 256, 0, stream>>>(h, agg, cnt, node_features,
                                                         W1np, W2np, b1n, b2n, d_out, flag);
}